// Round 2
// baseline (854.406 us; speedup 1.0000x reference)
//
#include <hip/hip_runtime.h>

// Problem constants: B=128, L=512, D=256, H=128, 4H=512, both dirs fused NG=1024
#define NB 128
#define NL 512
#define ND 256
#define NG 1024

typedef __attribute__((ext_vector_type(8))) short bfv8;
typedef __attribute__((ext_vector_type(4))) float f32x4;

__device__ __forceinline__ unsigned short f2bf(float f) {
    unsigned u = __float_as_uint(f);
    u += 0x7fffu + ((u >> 16) & 1u);   // round-to-nearest-even
    return (unsigned short)(u >> 16);
}
__device__ __forceinline__ float bf2f(unsigned short u) {
    return __uint_as_float(((unsigned)u) << 16);
}

// ---------------------------------------------------------------------------
// 1) convert+transpose: xbt[l*128+b][d] = bf16(x[b][l][d])
// ---------------------------------------------------------------------------
__global__ __launch_bounds__(256) void convert_kernel(const float* __restrict__ x,
                                                      unsigned short* __restrict__ xbt) {
    size_t t = (size_t)blockIdx.x * 256 + threadIdx.x;
    size_t e = t * 4;                       // flat idx into x, 4 floats per thread
    int d = (int)(e & 255u);
    int l = (int)((e >> 8) & 511u);
    int b = (int)(e >> 17);
    float4 v = *(const float4*)(x + e);
    ushort4 o;
    o.x = f2bf(v.x); o.y = f2bf(v.y); o.z = f2bf(v.z); o.w = f2bf(v.w);
    *(ushort4*)(xbt + ((size_t)(l * NB + b)) * ND + d) = o;
}

// ---------------------------------------------------------------------------
// 2) fold: Weff[g][k] = sum_d Wih[g][d] * W_proj[d][k]  (bf16 out)
//    beff[g] = b[g] + sum_d Wih[g][d] * b_proj[d]
// ---------------------------------------------------------------------------
__global__ __launch_bounds__(256) void fold_kernel(const float* __restrict__ Wproj,
                                                   const float* __restrict__ bproj,
                                                   const float* __restrict__ Wih_f,
                                                   const float* __restrict__ b_f,
                                                   const float* __restrict__ Wih_b,
                                                   const float* __restrict__ b_b,
                                                   unsigned short* __restrict__ weff,
                                                   float* __restrict__ beff) {
    int g = blockIdx.x;            // 0..1023
    int k = threadIdx.x;           // 0..255
    const float* Wih = (g < 512) ? (Wih_f + (size_t)g * ND) : (Wih_b + (size_t)(g - 512) * ND);
    float acc = 0.f;
    for (int d = 0; d < ND; ++d)
        acc += Wih[d] * Wproj[(size_t)d * ND + k];
    weff[(size_t)g * ND + k] = f2bf(acc);
    if (k == 0) {
        float ab = (g < 512) ? b_f[g] : b_b[g - 512];
        for (int d = 0; d < ND; ++d) ab += Wih[d] * bproj[d];
        beff[g] = ab;
    }
}

// ---------------------------------------------------------------------------
// 3) pre-GEMM: C[r][g] = bf16( A[r][:] . Bw[g][:] + bias[g] )
//    128x128 tile, BK=32, 4 waves (2x2), 16x16x32 bf16 MFMA, XOR-swizzled LDS
// ---------------------------------------------------------------------------
__global__ __launch_bounds__(256, 2) void gemm_pre(const unsigned short* __restrict__ A,
                                                   const unsigned short* __restrict__ Bw,
                                                   const float* __restrict__ bias,
                                                   unsigned short* __restrict__ C) {
    __shared__ unsigned short As[128 * 32];
    __shared__ unsigned short Bs[128 * 32];
    const int tid = threadIdx.x;
    const int lane = tid & 63;
    const int wid = tid >> 6;
    const int m0 = blockIdx.y * 128;
    const int n0 = blockIdx.x * 128;
    const int wm = (wid >> 1) * 64;
    const int wn = (wid & 1) * 64;

    f32x4 acc[4][4] = {};

    const int row0 = tid >> 2;               // 0..63
    const int row1 = row0 + 64;
    const int co = (tid & 3) * 8;            // element col offset (8 bf16 = 16B)
    const int sw = (((tid & 3) << 4) ^ ((row0 & 3) << 4)) >> 1;

    bfv8 ra0 = *(const bfv8*)(A + (size_t)(m0 + row0) * ND + co);
    bfv8 ra1 = *(const bfv8*)(A + (size_t)(m0 + row1) * ND + co);
    bfv8 rb0 = *(const bfv8*)(Bw + (size_t)(n0 + row0) * ND + co);
    bfv8 rb1 = *(const bfv8*)(Bw + (size_t)(n0 + row1) * ND + co);

    for (int it = 0; it < 8; ++it) {
        __syncthreads();
        *(bfv8*)(As + row0 * 32 + sw) = ra0;
        *(bfv8*)(As + row1 * 32 + sw) = ra1;
        *(bfv8*)(Bs + row0 * 32 + sw) = rb0;
        *(bfv8*)(Bs + row1 * 32 + sw) = rb1;
        const int k1 = ((it + 1) & 7) * 32;
        ra0 = *(const bfv8*)(A + (size_t)(m0 + row0) * ND + k1 + co);
        ra1 = *(const bfv8*)(A + (size_t)(m0 + row1) * ND + k1 + co);
        rb0 = *(const bfv8*)(Bw + (size_t)(n0 + row0) * ND + k1 + co);
        rb1 = *(const bfv8*)(Bw + (size_t)(n0 + row1) * ND + k1 + co);
        __syncthreads();

        const int r = lane & 15;
        const int kq = lane >> 4;
        bfv8 af[4], bfr[4];
        #pragma unroll
        for (int m = 0; m < 4; ++m) {
            int rw = wm + m * 16 + r;
            af[m] = *(const bfv8*)(As + rw * 32 + (((kq << 4) ^ ((rw & 3) << 4)) >> 1));
        }
        #pragma unroll
        for (int n = 0; n < 4; ++n) {
            int rw = wn + n * 16 + r;
            bfr[n] = *(const bfv8*)(Bs + rw * 32 + (((kq << 4) ^ ((rw & 3) << 4)) >> 1));
        }
        #pragma unroll
        for (int m = 0; m < 4; ++m)
            #pragma unroll
            for (int n = 0; n < 4; ++n)
                acc[m][n] = __builtin_amdgcn_mfma_f32_16x16x32_bf16(af[m], bfr[n], acc[m][n], 0, 0, 0);
    }

    const int r = lane & 15;
    const int rq = lane >> 4;
    #pragma unroll
    for (int n = 0; n < 4; ++n) {
        int col = n0 + wn + n * 16 + r;
        float bv = bias[col];
        #pragma unroll
        for (int m = 0; m < 4; ++m) {
            #pragma unroll
            for (int v = 0; v < 4; ++v) {
                int rowg = m0 + wm + m * 16 + rq * 4 + v;
                C[(size_t)rowg * NG + col] = f2bf(acc[m][n][v] + bv);
            }
        }
    }
}

// ---------------------------------------------------------------------------
// 4) LSTM scan: one block per (batch, dir). 1024 threads:
//    j bit0   = K-half (64 of 128 h-weights)
//    j bits1-2= gate type (i,f,g,o)
//    j bits3+ = hidden unit (0..127)
//    64 weights/thread in 16 f32x4 VGPRs (fits 128-VGPR cap of (1024,4)).
//    h broadcast from LDS (double-buffered), K-halves + gates exchanged via
//    shfl_xor -> ONE barrier per step.
// ---------------------------------------------------------------------------
__global__ __launch_bounds__(1024, 4) void scan_kernel(const unsigned short* __restrict__ pre,
                                                       const float* __restrict__ Whh_f,
                                                       const float* __restrict__ Whh_b,
                                                       float* __restrict__ out) {
    const int b = blockIdx.x;
    const int dir = blockIdx.y;
    const int j = threadIdx.x;
    const int kh = j & 1;            // K-half
    const int t4 = (j >> 1) & 3;     // gate type: 0=i,1=f,2=g,3=o
    const int hidx = j >> 3;         // hidden unit
    const int gidx = t4 * 128 + hidx;
    const float* __restrict__ Whh = (dir ? Whh_b : Whh_f) + (size_t)gidx * 128 + kh * 64;

    __shared__ float hbuf[2][128];

    f32x4 w[16];
    #pragma unroll
    for (int kk = 0; kk < 16; ++kk)
        w[kk] = *(const f32x4*)(Whh + kk * 4);

    if (j < 128) hbuf[0][j] = 0.f;
    float c = 0.f;
    const size_t pcol = (size_t)dir * 512 + gidx;
    const int tt0 = dir ? 511 : 0;
    float pnext = bf2f(pre[(size_t)(tt0 * NB + b) * NG + pcol]);
    __syncthreads();

    for (int s = 0; s < 512; ++s) {
        const int rb = s & 1;
        float gin = pnext;
        {   // prefetch next step's pre (independent of h -> hides HBM latency)
            int s1 = (s < 511) ? (s + 1) : 511;
            int tt1 = dir ? (511 - s1) : s1;
            pnext = bf2f(pre[(size_t)(tt1 * NB + b) * NG + pcol]);
        }
        const f32x4* hv = (const f32x4*)(&hbuf[rb][kh * 64]);
        f32x4 a = {0.f, 0.f, 0.f, 0.f};
        #pragma unroll
        for (int kk = 0; kk < 16; ++kk)
            a += w[kk] * hv[kk];
        float s01 = (a.x + a.y) + (a.z + a.w);
        float g = gin + s01 + __shfl_xor(s01, 1);   // combine K-halves

        // activation: sigmoid for i,f,o ; tanh for g
        float xg = (t4 == 2) ? 2.f * g : -g;
        float ev = __expf(xg);
        float act = (t4 == 2) ? (1.f - 2.f / (1.f + ev)) : (1.f / (1.f + ev));
        // exchange the 4 gate values within the 8-lane group (type bits are 1-2)
        float x0 = __shfl_xor(act, 2);   // type t^1
        float x1 = __shfl_xor(act, 4);   // type t^2
        float x2 = __shfl_xor(x0, 4);    // type t^3
        bool b0 = (t4 & 1) != 0, b1 = (t4 & 2) != 0;
        float gi = b1 ? (b0 ? x2 : x1) : (b0 ? x0 : act);
        float gf = b1 ? (b0 ? x1 : x2) : (b0 ? act : x0);
        float gg = b1 ? (b0 ? x0 : act) : (b0 ? x2 : x1);
        float go = b1 ? (b0 ? act : x0) : (b0 ? x1 : x2);
        c = gf * c + gi * gg;
        float th = 1.f - 2.f / (1.f + __expf(2.f * c));
        float h = go * th;
        if ((j & 7) == 0) {
            int tt = dir ? (511 - s) : s;
            hbuf[1 - rb][hidx] = h;
            out[((size_t)b * NL + tt) * 256 + dir * 128 + hidx] = h;
        }
        __syncthreads();
    }
}

// ---------------------------------------------------------------------------
// 5) LayerNorm in-place over last dim (256); one wave per row
// ---------------------------------------------------------------------------
__global__ __launch_bounds__(256) void ln_kernel(float* __restrict__ out,
                                                 const float* __restrict__ gamma,
                                                 const float* __restrict__ beta) {
    int row = blockIdx.x * 4 + (threadIdx.x >> 6);
    int lane = threadIdx.x & 63;
    float* p = out + (size_t)row * 256;
    float4 v = ((const float4*)p)[lane];
    float s = (v.x + v.y) + (v.z + v.w);
    float s2 = (v.x * v.x + v.y * v.y) + (v.z * v.z + v.w * v.w);
    #pragma unroll
    for (int o = 32; o > 0; o >>= 1) {
        s += __shfl_xor(s, o);
        s2 += __shfl_xor(s2, o);
    }
    float mu = s * (1.f / 256.f);
    float var = s2 * (1.f / 256.f) - mu * mu;
    float rs = rsqrtf(var + 1e-5f);
    float4 gv = ((const float4*)gamma)[lane];
    float4 bv = ((const float4*)beta)[lane];
    float4 r;
    r.x = (v.x - mu) * rs * gv.x + bv.x;
    r.y = (v.y - mu) * rs * gv.y + bv.y;
    r.z = (v.z - mu) * rs * gv.z + bv.z;
    r.w = (v.w - mu) * rs * gv.w + bv.w;
    ((float4*)p)[lane] = r;
}

// ---------------------------------------------------------------------------
extern "C" void kernel_launch(void* const* d_in, const int* in_sizes, int n_in,
                              void* d_out, int out_size, void* d_ws, size_t ws_size,
                              hipStream_t stream) {
    (void)in_sizes; (void)n_in; (void)out_size; (void)ws_size;
    const float* x     = (const float*)d_in[0];
    const float* Wproj = (const float*)d_in[1];
    const float* bproj = (const float*)d_in[2];
    const float* Wih_f = (const float*)d_in[3];
    const float* Whh_f = (const float*)d_in[4];
    const float* b_f   = (const float*)d_in[5];
    const float* Wih_b = (const float*)d_in[6];
    const float* Whh_b = (const float*)d_in[7];
    const float* b_b   = (const float*)d_in[8];
    const float* gamma = (const float*)d_in[9];
    const float* beta  = (const float*)d_in[10];
    float* out = (float*)d_out;

    // workspace layout
    char* ws = (char*)d_ws;
    unsigned short* pre  = (unsigned short*)ws;                   // 65536*1024*2 = 134217728
    unsigned short* xbt  = (unsigned short*)(ws + 134217728);     // 65536*256*2  =  33554432
    unsigned short* weff = (unsigned short*)(ws + 167772160);     // 1024*256*2   =    524288
    float*          beff = (float*)(ws + 168296448);              // 1024*4

    convert_kernel<<<16384, 256, 0, stream>>>(x, xbt);
    fold_kernel<<<1024, 256, 0, stream>>>(Wproj, bproj, Wih_f, b_f, Wih_b, b_b, weff, beff);
    gemm_pre<<<dim3(8, 512), 256, 0, stream>>>(xbt, weff, beff, pre);
    scan_kernel<<<dim3(128, 2), 1024, 0, stream>>>(pre, Whh_f, Whh_b, out);
    ln_kernel<<<16384, 256, 0, stream>>>(out, gamma, beta);
}

// Round 3
// 584.341 us; speedup vs baseline: 1.4622x; 1.4622x over previous
//
#include <hip/hip_runtime.h>

// Problem constants: B=128, L=512, D=256, H=128, 4H=512, both dirs fused NG=1024
#define NB 128
#define NL 512
#define ND 256
#define NG 1024

typedef __attribute__((ext_vector_type(8))) short bfv8;
typedef __attribute__((ext_vector_type(4))) float f32x4;

__device__ __forceinline__ unsigned short f2bf(float f) {
    unsigned u = __float_as_uint(f);
    u += 0x7fffu + ((u >> 16) & 1u);   // round-to-nearest-even
    return (unsigned short)(u >> 16);
}
__device__ __forceinline__ float bf2f(unsigned short u) {
    return __uint_as_float(((unsigned)u) << 16);
}

// ---------------------------------------------------------------------------
// 1) convert+transpose: xbt[l*128+b][d] = bf16(x[b][l][d])
// ---------------------------------------------------------------------------
__global__ __launch_bounds__(256) void convert_kernel(const float* __restrict__ x,
                                                      unsigned short* __restrict__ xbt) {
    size_t t = (size_t)blockIdx.x * 256 + threadIdx.x;
    size_t e = t * 4;                       // flat idx into x, 4 floats per thread
    int d = (int)(e & 255u);
    int l = (int)((e >> 8) & 511u);
    int b = (int)(e >> 17);
    float4 v = *(const float4*)(x + e);
    ushort4 o;
    o.x = f2bf(v.x); o.y = f2bf(v.y); o.z = f2bf(v.z); o.w = f2bf(v.w);
    *(ushort4*)(xbt + ((size_t)(l * NB + b)) * ND + d) = o;
}

// ---------------------------------------------------------------------------
// 2) fold: Weff[g][k] = sum_d Wih[g][d] * W_proj[d][k]  (bf16 out)
//    beff[g] = b[g] + sum_d Wih[g][d] * b_proj[d]
// ---------------------------------------------------------------------------
__global__ __launch_bounds__(256) void fold_kernel(const float* __restrict__ Wproj,
                                                   const float* __restrict__ bproj,
                                                   const float* __restrict__ Wih_f,
                                                   const float* __restrict__ b_f,
                                                   const float* __restrict__ Wih_b,
                                                   const float* __restrict__ b_b,
                                                   unsigned short* __restrict__ weff,
                                                   float* __restrict__ beff) {
    int g = blockIdx.x;            // 0..1023
    int k = threadIdx.x;           // 0..255
    const float* Wih = (g < 512) ? (Wih_f + (size_t)g * ND) : (Wih_b + (size_t)(g - 512) * ND);
    float acc = 0.f;
    for (int d = 0; d < ND; ++d)
        acc += Wih[d] * Wproj[(size_t)d * ND + k];
    weff[(size_t)g * ND + k] = f2bf(acc);
    if (k == 0) {
        float ab = (g < 512) ? b_f[g] : b_b[g - 512];
        for (int d = 0; d < ND; ++d) ab += Wih[d] * bproj[d];
        beff[g] = ab;
    }
}

// ---------------------------------------------------------------------------
// 3) pre-GEMM: C[r][g] = bf16( A[r][:] . Bw[g][:] + bias[g] )
//    128x128 tile, BK=32, 4 waves (2x2), 16x16x32 bf16 MFMA, XOR-swizzled LDS
// ---------------------------------------------------------------------------
__global__ __launch_bounds__(256, 2) void gemm_pre(const unsigned short* __restrict__ A,
                                                   const unsigned short* __restrict__ Bw,
                                                   const float* __restrict__ bias,
                                                   unsigned short* __restrict__ C) {
    __shared__ unsigned short As[128 * 32];
    __shared__ unsigned short Bs[128 * 32];
    const int tid = threadIdx.x;
    const int lane = tid & 63;
    const int wid = tid >> 6;
    const int m0 = blockIdx.y * 128;
    const int n0 = blockIdx.x * 128;
    const int wm = (wid >> 1) * 64;
    const int wn = (wid & 1) * 64;

    f32x4 acc[4][4] = {};

    const int row0 = tid >> 2;               // 0..63
    const int row1 = row0 + 64;
    const int co = (tid & 3) * 8;            // element col offset (8 bf16 = 16B)
    const int sw = (((tid & 3) << 4) ^ ((row0 & 3) << 4)) >> 1;

    bfv8 ra0 = *(const bfv8*)(A + (size_t)(m0 + row0) * ND + co);
    bfv8 ra1 = *(const bfv8*)(A + (size_t)(m0 + row1) * ND + co);
    bfv8 rb0 = *(const bfv8*)(Bw + (size_t)(n0 + row0) * ND + co);
    bfv8 rb1 = *(const bfv8*)(Bw + (size_t)(n0 + row1) * ND + co);

    for (int it = 0; it < 8; ++it) {
        __syncthreads();
        *(bfv8*)(As + row0 * 32 + sw) = ra0;
        *(bfv8*)(As + row1 * 32 + sw) = ra1;
        *(bfv8*)(Bs + row0 * 32 + sw) = rb0;
        *(bfv8*)(Bs + row1 * 32 + sw) = rb1;
        const int k1 = ((it + 1) & 7) * 32;
        ra0 = *(const bfv8*)(A + (size_t)(m0 + row0) * ND + k1 + co);
        ra1 = *(const bfv8*)(A + (size_t)(m0 + row1) * ND + k1 + co);
        rb0 = *(const bfv8*)(Bw + (size_t)(n0 + row0) * ND + k1 + co);
        rb1 = *(const bfv8*)(Bw + (size_t)(n0 + row1) * ND + k1 + co);
        __syncthreads();

        const int r = lane & 15;
        const int kq = lane >> 4;
        bfv8 af[4], bfr[4];
        #pragma unroll
        for (int m = 0; m < 4; ++m) {
            int rw = wm + m * 16 + r;
            af[m] = *(const bfv8*)(As + rw * 32 + (((kq << 4) ^ ((rw & 3) << 4)) >> 1));
        }
        #pragma unroll
        for (int n = 0; n < 4; ++n) {
            int rw = wn + n * 16 + r;
            bfr[n] = *(const bfv8*)(Bs + rw * 32 + (((kq << 4) ^ ((rw & 3) << 4)) >> 1));
        }
        #pragma unroll
        for (int m = 0; m < 4; ++m)
            #pragma unroll
            for (int n = 0; n < 4; ++n)
                acc[m][n] = __builtin_amdgcn_mfma_f32_16x16x32_bf16(af[m], bfr[n], acc[m][n], 0, 0, 0);
    }

    const int r = lane & 15;
    const int rq = lane >> 4;
    #pragma unroll
    for (int n = 0; n < 4; ++n) {
        int col = n0 + wn + n * 16 + r;
        float bv = bias[col];
        #pragma unroll
        for (int m = 0; m < 4; ++m) {
            #pragma unroll
            for (int v = 0; v < 4; ++v) {
                int rowg = m0 + wm + m * 16 + rq * 4 + v;
                C[(size_t)rowg * NG + col] = f2bf(acc[m][n][v] + bv);
            }
        }
    }
}

// ---------------------------------------------------------------------------
// 4) LSTM scan: one block per (batch, dir). 512 threads: thread j = gate type
//    (j&3) of hidden unit (j>>2). 128 weights/thread in 32 f32x4, PINNED in
//    VGPRs via asm (compiler was rematerializing the loads every step ->
//    L2-BW-bound). h broadcast from LDS (uniform address, conflict-free),
//    double-buffered, gate exchange via shfl_xor -> ONE barrier per step.
// ---------------------------------------------------------------------------
__global__ __launch_bounds__(512, 2) void scan_kernel(const unsigned short* __restrict__ pre,
                                                      const float* __restrict__ Whh_f,
                                                      const float* __restrict__ Whh_b,
                                                      float* __restrict__ out) {
    const int b = blockIdx.x;
    const int dir = blockIdx.y;
    const int j = threadIdx.x;
    const int t4 = j & 3;            // gate type: 0=i,1=f,2=g,3=o
    const int hidx = j >> 2;         // hidden unit
    const int gidx = t4 * 128 + hidx;
    const float* __restrict__ Whh = dir ? Whh_b : Whh_f;

    __shared__ float hbuf[2][128];

    f32x4 w[32];
    #pragma unroll
    for (int kk = 0; kk < 32; ++kk) {
        w[kk] = *(const f32x4*)(Whh + (size_t)gidx * 128 + kk * 4);
        asm volatile("" : "+v"(w[kk]));   // opaque def: blocks rematerialization
    }

    if (j < 128) hbuf[0][j] = 0.f;
    float c = 0.f;
    const size_t pcol = (size_t)dir * 512 + gidx;
    const int tt0 = dir ? 511 : 0;
    float pnext = bf2f(pre[(size_t)(tt0 * NB + b) * NG + pcol]);
    __syncthreads();

    for (int s = 0; s < 512; ++s) {
        const int rb = s & 1;
        float gin = pnext;
        {   // prefetch next step's pre (independent of h -> hides HBM latency)
            int s1 = (s < 511) ? (s + 1) : 511;
            int tt1 = dir ? (511 - s1) : s1;
            pnext = bf2f(pre[(size_t)(tt1 * NB + b) * NG + pcol]);
        }
        const f32x4* hv = (const f32x4*)hbuf[rb];
        f32x4 a = {0.f, 0.f, 0.f, 0.f};
        #pragma unroll
        for (int kk = 0; kk < 32; ++kk)
            a += w[kk] * hv[kk];          // v_pk_fma_f32 pairs, broadcast LDS reads
        float g = gin + (a.x + a.y) + (a.z + a.w);

        // activation: sigmoid for i,f,o ; tanh for g
        float xg = (t4 == 2) ? 2.f * g : -g;
        float ev = __expf(xg);
        float act = (t4 == 2) ? (1.f - 2.f / (1.f + ev)) : (1.f / (1.f + ev));
        // exchange the 4 gate values within the 4-lane group
        float x0 = __shfl_xor(act, 1);   // type t^1
        float x1 = __shfl_xor(act, 2);   // type t^2
        float x2 = __shfl_xor(x0, 2);    // type t^3
        bool b0 = (t4 & 1) != 0, b1 = (t4 & 2) != 0;
        float gi = b1 ? (b0 ? x2 : x1) : (b0 ? x0 : act);
        float gf = b1 ? (b0 ? x1 : x2) : (b0 ? act : x0);
        float gg = b1 ? (b0 ? x0 : act) : (b0 ? x2 : x1);
        float go = b1 ? (b0 ? act : x0) : (b0 ? x1 : x2);
        c = gf * c + gi * gg;
        float th = 1.f - 2.f / (1.f + __expf(2.f * c));
        float h = go * th;
        if (t4 == 0) {
            int tt = dir ? (511 - s) : s;
            hbuf[1 - rb][hidx] = h;
            out[((size_t)b * NL + tt) * 256 + dir * 128 + hidx] = h;
        }
        __syncthreads();
    }
}

// ---------------------------------------------------------------------------
// 5) LayerNorm in-place over last dim (256); one wave per row
// ---------------------------------------------------------------------------
__global__ __launch_bounds__(256) void ln_kernel(float* __restrict__ out,
                                                 const float* __restrict__ gamma,
                                                 const float* __restrict__ beta) {
    int row = blockIdx.x * 4 + (threadIdx.x >> 6);
    int lane = threadIdx.x & 63;
    float* p = out + (size_t)row * 256;
    float4 v = ((const float4*)p)[lane];
    float s = (v.x + v.y) + (v.z + v.w);
    float s2 = (v.x * v.x + v.y * v.y) + (v.z * v.z + v.w * v.w);
    #pragma unroll
    for (int o = 32; o > 0; o >>= 1) {
        s += __shfl_xor(s, o);
        s2 += __shfl_xor(s2, o);
    }
    float mu = s * (1.f / 256.f);
    float var = s2 * (1.f / 256.f) - mu * mu;
    float rs = rsqrtf(var + 1e-5f);
    float4 gv = ((const float4*)gamma)[lane];
    float4 bv = ((const float4*)beta)[lane];
    float4 r;
    r.x = (v.x - mu) * rs * gv.x + bv.x;
    r.y = (v.y - mu) * rs * gv.y + bv.y;
    r.z = (v.z - mu) * rs * gv.z + bv.z;
    r.w = (v.w - mu) * rs * gv.w + bv.w;
    ((float4*)p)[lane] = r;
}

// ---------------------------------------------------------------------------
extern "C" void kernel_launch(void* const* d_in, const int* in_sizes, int n_in,
                              void* d_out, int out_size, void* d_ws, size_t ws_size,
                              hipStream_t stream) {
    (void)in_sizes; (void)n_in; (void)out_size; (void)ws_size;
    const float* x     = (const float*)d_in[0];
    const float* Wproj = (const float*)d_in[1];
    const float* bproj = (const float*)d_in[2];
    const float* Wih_f = (const float*)d_in[3];
    const float* Whh_f = (const float*)d_in[4];
    const float* b_f   = (const float*)d_in[5];
    const float* Wih_b = (const float*)d_in[6];
    const float* Whh_b = (const float*)d_in[7];
    const float* b_b   = (const float*)d_in[8];
    const float* gamma = (const float*)d_in[9];
    const float* beta  = (const float*)d_in[10];
    float* out = (float*)d_out;

    // workspace layout
    char* ws = (char*)d_ws;
    unsigned short* pre  = (unsigned short*)ws;                   // 65536*1024*2 = 134217728
    unsigned short* xbt  = (unsigned short*)(ws + 134217728);     // 65536*256*2  =  33554432
    unsigned short* weff = (unsigned short*)(ws + 167772160);     // 1024*256*2   =    524288
    float*          beff = (float*)(ws + 168296448);              // 1024*4

    convert_kernel<<<16384, 256, 0, stream>>>(x, xbt);
    fold_kernel<<<1024, 256, 0, stream>>>(Wproj, bproj, Wih_f, b_f, Wih_b, b_b, weff, beff);
    gemm_pre<<<dim3(8, 512), 256, 0, stream>>>(xbt, weff, beff, pre);
    scan_kernel<<<dim3(128, 2), 512, 0, stream>>>(pre, Whh_f, Whh_b, out);
    ln_kernel<<<16384, 256, 0, stream>>>(out, gamma, beta);
}